// Round 2
// baseline (3899.933 us; speedup 1.0000x reference)
//
#include <hip/hip_runtime.h>
#include <hip/hip_bf16.h>

// ---------------------------------------------------------------------------
// DeltaNet forward. B=2, S=1024, D=1024, L=2, V=32000.
// R1: head GEMM -> bf16 MFMA (verified, absmax unchanged).
// R2: delta_scan rewrite (was 2x1195us, 2e8 LDS bank conflicts, 2800 cy/step):
//     - conflict-free lane->d mapping (m97 ds_read_b128 pattern, 8 words/bank)
//     - global_load_lds double-buffered staging, ONE raw s_barrier per step,
//       vmcnt(0) drain of own stages only (loads hide under compute)
//     - merged reduce: o = q.S_old + (q.k)u -> 3 interleaved shuffle chains
//     Layer GEMMs stay fp32 this round.
// ---------------------------------------------------------------------------

#define DD 1024
#define BB 2
#define SS 1024
#define LL 2
#define VV 32000

typedef __attribute__((ext_vector_type(8))) short bf16x8;
typedef __attribute__((ext_vector_type(4))) float f32x4;

__device__ __forceinline__ float sigmoidf_(float x) { return 1.0f / (1.0f + expf(-x)); }

// round-to-nearest-even f32 -> bf16
__device__ __forceinline__ unsigned short f2bf(float f) {
    unsigned int u = __float_as_uint(f);
    u += 0x7fffu + ((u >> 16) & 1u);
    return (unsigned short)(u >> 16);
}

// ---------------- embedding gather ----------------
__global__ __launch_bounds__(256) void gather_rows(const int* __restrict__ tokens,
                                                   const float* __restrict__ emb,
                                                   float* __restrict__ x) {
    int row = blockIdx.x;
    int tok = tokens[row];
    const float4* src = (const float4*)(emb + (size_t)tok * DD);
    float4* dst = (float4*)(x + (size_t)row * DD);
    for (int i = threadIdx.x; i < DD / 4; i += 256) dst[i] = src[i];
}

// ---------------- generic tiled SGEMM (fp32, layer GEMMs) ----------------
template <int BM, int BN, int BK, int TM, int TN>
__global__ __launch_bounds__(256) void sgemm(const float* __restrict__ A,
                                             const float* __restrict__ B,
                                             float* __restrict__ C,
                                             int M, int N, int K) {
    constexpr int THREADS = (BM / TM) * (BN / TN);
    static_assert(THREADS == 256, "block must be 256");
    __shared__ float As[BK][BM + 4];
    __shared__ float Bs[BK][BN + 4];

    const int tid = threadIdx.x;
    const int tx = tid % (BN / TN);
    const int ty = tid / (BN / TN);
    const int row0 = blockIdx.y * BM;
    const int col0 = blockIdx.x * BN;

    float acc[TM][TN] = {};

    for (int k0 = 0; k0 < K; k0 += BK) {
        constexpr int A4 = BM * BK / 4;
        #pragma unroll
        for (int i = tid; i < A4; i += THREADS) {
            int r = i / (BK / 4);
            int q = i % (BK / 4);
            float4 f = *(const float4*)&A[(size_t)(row0 + r) * K + k0 + q * 4];
            As[q * 4 + 0][r] = f.x;
            As[q * 4 + 1][r] = f.y;
            As[q * 4 + 2][r] = f.z;
            As[q * 4 + 3][r] = f.w;
        }
        constexpr int B4 = BK * BN / 4;
        #pragma unroll
        for (int i = tid; i < B4; i += THREADS) {
            int r = i / (BN / 4);
            int q = i % (BN / 4);
            float4 f = *(const float4*)&B[(size_t)(k0 + r) * N + col0 + q * 4];
            *(float4*)&Bs[r][q * 4] = f;
        }
        __syncthreads();

        #pragma unroll
        for (int kr = 0; kr < BK; kr++) {
            float a[TM], b[TN];
            #pragma unroll
            for (int i = 0; i < TM; i += 4)
                *(float4*)&a[i] = *(const float4*)&As[kr][ty * TM + i];
            #pragma unroll
            for (int j = 0; j < TN; j += 4)
                *(float4*)&b[j] = *(const float4*)&Bs[kr][tx * TN + j];
            #pragma unroll
            for (int i = 0; i < TM; i++)
                #pragma unroll
                for (int j = 0; j < TN; j++)
                    acc[i][j] += a[i] * b[j];
        }
        __syncthreads();
    }

    #pragma unroll
    for (int i = 0; i < TM; i++)
        #pragma unroll
        for (int j = 0; j < TN; j += 4) {
            float4 f = {acc[i][j], acc[i][j + 1], acc[i][j + 2], acc[i][j + 3]};
            *(float4*)&C[(size_t)(row0 + ty * TM + i) * N + col0 + tx * TN + j] = f;
        }
}

// ---------------- bf16 MFMA GEMM (head) ----------------
__global__ __launch_bounds__(256) void gemm_bf16_tn(const unsigned short* __restrict__ A,
                                                    const unsigned short* __restrict__ Bt,
                                                    float* __restrict__ C,
                                                    int M, int N, int K) {
    __shared__ __align__(16) unsigned short As[128 * 32];
    __shared__ __align__(16) unsigned short Bs[128 * 32];

    const int tid = threadIdx.x;
    const int wave = tid >> 6;
    const int lane = tid & 63;
    const int row0 = blockIdx.y * 128;
    const int col0 = blockIdx.x * 128;
    const int wm = wave >> 1;
    const int wn = wave & 1;
    const int g = lane >> 4;
    const int fr = lane & 15;

    const int lr = lane >> 2;
    const int lk = (lane & 3) * 8;

    f32x4 acc[4][4] = {};

    for (int k0 = 0; k0 < K; k0 += 32) {
        __syncthreads();
        #pragma unroll
        for (int i = 0; i < 2; i++) {
            const int iss = wave * 2 + i;
            const unsigned short* ga = A + (size_t)(row0 + iss * 16 + lr) * K + k0 + lk;
            __builtin_amdgcn_global_load_lds(
                (const __attribute__((address_space(1))) void*)ga,
                (__attribute__((address_space(3))) void*)(As + iss * 512), 16, 0, 0);
            const unsigned short* gb = Bt + (size_t)(col0 + iss * 16 + lr) * K + k0 + lk;
            __builtin_amdgcn_global_load_lds(
                (const __attribute__((address_space(1))) void*)gb,
                (__attribute__((address_space(3))) void*)(Bs + iss * 512), 16, 0, 0);
        }
        __syncthreads();

        bf16x8 a[4], b[4];
        #pragma unroll
        for (int i = 0; i < 4; i++)
            a[i] = *(const bf16x8*)&As[(wm * 64 + i * 16 + fr) * 32 + g * 8];
        #pragma unroll
        for (int j = 0; j < 4; j++)
            b[j] = *(const bf16x8*)&Bs[(wn * 64 + j * 16 + fr) * 32 + g * 8];
        #pragma unroll
        for (int i = 0; i < 4; i++)
            #pragma unroll
            for (int j = 0; j < 4; j++)
                acc[i][j] = __builtin_amdgcn_mfma_f32_16x16x32_bf16(a[i], b[j], acc[i][j], 0, 0, 0);
    }

    #pragma unroll
    for (int i = 0; i < 4; i++) {
        const int rbase = row0 + wm * 64 + i * 16 + g * 4;
        #pragma unroll
        for (int j = 0; j < 4; j++) {
            const int c = col0 + wn * 64 + j * 16 + fr;
            #pragma unroll
            for (int ii = 0; ii < 4; ii++)
                C[(size_t)(rbase + ii) * N + c] = acc[i][j][ii];
        }
    }
}

// ---------------- f32 -> bf16 converters ----------------
__global__ __launch_bounds__(256) void f32_to_bf16_vec(const float* __restrict__ in,
                                                       unsigned short* __restrict__ out,
                                                       int n4) {
    int i = blockIdx.x * 256 + threadIdx.x;
    if (i < n4) {
        float4 f = ((const float4*)in)[i];
        ushort4 u = {f2bf(f.x), f2bf(f.y), f2bf(f.z), f2bf(f.w)};
        ((ushort4*)out)[i] = u;
    }
}

__global__ __launch_bounds__(256) void transpose_f32_bf16(const float* __restrict__ in,
                                                          unsigned short* __restrict__ out,
                                                          int K, int N) {
    __shared__ float tile[32][33];
    const int nb = blockIdx.x;
    const int kb = blockIdx.y;
    const int tx = threadIdx.x & 31;
    const int ty = threadIdx.x >> 5;
    #pragma unroll
    for (int i = 0; i < 32; i += 8)
        tile[ty + i][tx] = in[(size_t)(kb * 32 + ty + i) * N + nb * 32 + tx];
    __syncthreads();
    #pragma unroll
    for (int i = 0; i < 32; i += 8)
        out[(size_t)(nb * 32 + ty + i) * K + kb * 32 + tx] = f2bf(tile[tx][ty + i]);
}

// ---------------- activations ----------------
__global__ __launch_bounds__(256) void silu_l2norm_kernel(float* __restrict__ buf) {
    __shared__ float tmp[4];
    size_t base = (size_t)blockIdx.x * DD;
    float vals[4];
    float ss = 0.0f;
    #pragma unroll
    for (int i = 0; i < 4; i++) {
        float xv = buf[base + threadIdx.x + i * 256];
        float s = xv * sigmoidf_(xv);
        vals[i] = s;
        ss += s * s;
    }
    #pragma unroll
    for (int off = 32; off; off >>= 1) ss += __shfl_xor(ss, off);
    if ((threadIdx.x & 63) == 0) tmp[threadIdx.x >> 6] = ss;
    __syncthreads();
    ss = tmp[0] + tmp[1] + tmp[2] + tmp[3];
    float sc = rsqrtf(ss + 1e-6f);
    #pragma unroll
    for (int i = 0; i < 4; i++) buf[base + threadIdx.x + i * 256] = vals[i] * sc;
}

__global__ __launch_bounds__(256) void silu_kernel(float* __restrict__ buf, int n) {
    int i = blockIdx.x * 256 + threadIdx.x;
    if (i < n) {
        float xv = buf[i];
        buf[i] = xv * sigmoidf_(xv);
    }
}

__global__ __launch_bounds__(256) void beta_kernel(const float* __restrict__ x,
                                                   const float* __restrict__ wb,
                                                   float* __restrict__ beta) {
    __shared__ float tmp[4];
    size_t base = (size_t)blockIdx.x * DD;
    float s = 0.0f;
    #pragma unroll
    for (int i = 0; i < 4; i++) {
        int idx = threadIdx.x + i * 256;
        s += x[base + idx] * wb[idx];
    }
    #pragma unroll
    for (int off = 32; off; off >>= 1) s += __shfl_xor(s, off);
    if ((threadIdx.x & 63) == 0) tmp[threadIdx.x >> 6] = s;
    __syncthreads();
    if (threadIdx.x == 0) beta[blockIdx.x] = sigmoidf_(tmp[0] + tmp[1] + tmp[2] + tmp[3]);
}

__global__ __launch_bounds__(256) void rmsnorm_kernel(float* __restrict__ buf,
                                                      const float* __restrict__ w) {
    __shared__ float tmp[4];
    size_t base = (size_t)blockIdx.x * DD;
    float vals[4];
    float ss = 0.0f;
    #pragma unroll
    for (int i = 0; i < 4; i++) {
        float xv = buf[base + threadIdx.x + i * 256];
        vals[i] = xv;
        ss += xv * xv;
    }
    #pragma unroll
    for (int off = 32; off; off >>= 1) ss += __shfl_xor(ss, off);
    if ((threadIdx.x & 63) == 0) tmp[threadIdx.x >> 6] = ss;
    __syncthreads();
    ss = tmp[0] + tmp[1] + tmp[2] + tmp[3];
    float sc = rsqrtf(ss * (1.0f / DD) + 1e-5f);
    #pragma unroll
    for (int i = 0; i < 4; i++) {
        int idx = threadIdx.x + i * 256;
        buf[base + idx] = vals[i] * sc * w[idx];
    }
}

__global__ __launch_bounds__(256) void layernorm_kernel(const float* __restrict__ in,
                                                        const float* __restrict__ g,
                                                        const float* __restrict__ b,
                                                        float* __restrict__ out) {
    __shared__ float tmp[4];
    size_t base = (size_t)blockIdx.x * DD;
    float vals[4];
    float s = 0.0f;
    #pragma unroll
    for (int i = 0; i < 4; i++) {
        float xv = in[base + threadIdx.x + i * 256];
        vals[i] = xv;
        s += xv;
    }
    #pragma unroll
    for (int off = 32; off; off >>= 1) s += __shfl_xor(s, off);
    if ((threadIdx.x & 63) == 0) tmp[threadIdx.x >> 6] = s;
    __syncthreads();
    float mu = (tmp[0] + tmp[1] + tmp[2] + tmp[3]) * (1.0f / DD);
    float vs = 0.0f;
    #pragma unroll
    for (int i = 0; i < 4; i++) {
        float c = vals[i] - mu;
        vals[i] = c;
        vs += c * c;
    }
    #pragma unroll
    for (int off = 32; off; off >>= 1) vs += __shfl_xor(vs, off);
    __syncthreads();
    if ((threadIdx.x & 63) == 0) tmp[threadIdx.x >> 6] = vs;
    __syncthreads();
    float var = (tmp[0] + tmp[1] + tmp[2] + tmp[3]) * (1.0f / DD);
    float sc = rsqrtf(var + 1e-5f);
    #pragma unroll
    for (int i = 0; i < 4; i++) {
        int idx = threadIdx.x + i * 256;
        out[base + idx] = vals[i] * sc * g[idx] + b[idx];
    }
}

// ---------------- delta-rule scan (R2) ----------------
// State S[d][e] per batch, column-parallel: wave w of block owns column
// col = (blockIdx.x % 256)*4 + w. Lane (g=lane>>4, fr=lane&15) owns rows
// d = r4*256 + fr*16 + g*4 + i  (r4=0..3, i=0..3)  -> ds_read_b128 at word
// fr*16+g*4: uniform 8 words/bank (m97 pattern, conflict-free).
// k,q rows double-buffered in LDS via global_load_lds (width 16), staged one
// step ahead; ONE raw s_barrier per step after draining own stage loads.
// Merged epilogue: o = q.S_old + (q.k)*u  -> 3 interleaved shuffle reduces.
__global__ __launch_bounds__(256) void delta_scan_kernel(const float* __restrict__ q,
                                                         const float* __restrict__ k,
                                                         const float* __restrict__ v,
                                                         const float* __restrict__ beta,
                                                         float* __restrict__ o) {
    __shared__ __align__(16) float lk[2][DD];
    __shared__ __align__(16) float lq[2][DD];
    const int nColBlk = DD / 4;                 // 256
    const int batch = blockIdx.x / nColBlk;
    const int colBase = (blockIdx.x % nColBlk) * 4;
    const int w = threadIdx.x >> 6;
    const int lane = threadIdx.x & 63;
    const int fr = lane & 15;
    const int g = lane >> 4;
    const int col = colBase + w;
    const size_t base = (size_t)batch * SS * DD;
    const int dbase = fr * 16 + g * 4;          // word offset within 256-block
    const int stoff = w * 256 + lane * 4;       // staging: wave w covers floats [w*256, w*256+256)

    float Sl[16];
    #pragma unroll
    for (int r = 0; r < 16; r++) Sl[r] = 0.0f;

    // prologue: stage t=0 into buf 0
    {
        const float* gk = k + base + stoff;
        const float* gq = q + base + stoff;
        __builtin_amdgcn_global_load_lds(
            (const __attribute__((address_space(1))) void*)gk,
            (__attribute__((address_space(3))) void*)(&lk[0][w * 256]), 16, 0, 0);
        __builtin_amdgcn_global_load_lds(
            (const __attribute__((address_space(1))) void*)gq,
            (__attribute__((address_space(3))) void*)(&lq[0][w * 256]), 16, 0, 0);
    }

    for (int t = 0; t < SS; t++) {
        const int buf = t & 1;
        const size_t rowoff = base + (size_t)t * DD;

        // own stage loads for step t (issued last iter) are the only
        // outstanding vmem ops of consequence; drain, then align waves.
        asm volatile("s_waitcnt vmcnt(0)" ::: "memory");
        __builtin_amdgcn_s_barrier();

        // stage t+1 into the other buffer (safe: all waves are past their
        // reads of it — data was consumed in registers before barrier).
        if (t + 1 < SS) {
            const float* gk = k + rowoff + DD + stoff;
            const float* gq = q + rowoff + DD + stoff;
            __builtin_amdgcn_global_load_lds(
                (const __attribute__((address_space(1))) void*)gk,
                (__attribute__((address_space(3))) void*)(&lk[buf ^ 1][w * 256]), 16, 0, 0);
            __builtin_amdgcn_global_load_lds(
                (const __attribute__((address_space(1))) void*)gq,
                (__attribute__((address_space(3))) void*)(&lq[buf ^ 1][w * 256]), 16, 0, 0);
        }

        // per-step scalars: issued here, consumed ~300cy later at u
        float bt = beta[batch * SS + t];
        float vt = v[rowoff + col];

        // conflict-free fragment reads
        float kk[16], qq[16];
        #pragma unroll
        for (int r4 = 0; r4 < 4; r4++) {
            *(float4*)&kk[r4 * 4] = *(const float4*)&lk[buf][r4 * 256 + dbase];
            *(float4*)&qq[r4 * 4] = *(const float4*)&lq[buf][r4 * 256 + dbase];
        }

        // three partial dots, reduced by interleaved (pipelined) shuffle chains
        float pk = 0.0f, pq = 0.0f, pqk = 0.0f;
        #pragma unroll
        for (int r = 0; r < 16; r++) {
            pk += kk[r] * Sl[r];
            pq += qq[r] * Sl[r];
            pqk += qq[r] * kk[r];
        }
        #pragma unroll
        for (int off = 32; off; off >>= 1) {
            pk += __shfl_xor(pk, off);
            pq += __shfl_xor(pq, off);
            pqk += __shfl_xor(pqk, off);
        }

        float u = bt * (vt - pk);
        float op = pq + pqk * u;   // == q . (S_old + k u)

        #pragma unroll
        for (int r = 0; r < 16; r++) Sl[r] += kk[r] * u;

        if (lane == 0) o[rowoff + col] = op;
    }
}

// ---------------------------------------------------------------------------
extern "C" void kernel_launch(void* const* d_in, const int* in_sizes, int n_in,
                              void* d_out, int out_size, void* d_ws, size_t ws_size,
                              hipStream_t stream) {
    const int* tokens   = (const int*)d_in[0];
    const float* emb    = (const float*)d_in[1];
    const float* Wq     = (const float*)d_in[2];
    const float* Wk     = (const float*)d_in[3];
    const float* Wv     = (const float*)d_in[4];
    const float* Wb     = (const float*)d_in[5];
    const float* Wo     = (const float*)d_in[6];
    const float* rms_w  = (const float*)d_in[7];
    const float* ln_g   = (const float*)d_in[8];
    const float* ln_b   = (const float*)d_in[9];
    const float* head_w = (const float*)d_in[10];
    float* out = (float*)d_out;

    const int M = BB * SS;  // 2048
    const size_t ND = (size_t)M * DD;

    float* ws    = (float*)d_ws;
    float* x     = ws;
    float* qb    = ws + ND;
    float* kb    = ws + 2 * ND;
    float* vb    = ws + 3 * ND;
    float* ob    = ws + 4 * ND;
    float* xn    = ws + 5 * ND;
    float* betab = ws + 6 * ND;  // M floats

    unsigned short* xnb = (unsigned short*)(ws + 6 * ND + M);
    unsigned short* hwb = xnb + (size_t)M * DD;
    const size_t need_bytes = (6 * ND + M) * sizeof(float) +
                              ((size_t)M * DD + (size_t)VV * DD) * sizeof(unsigned short);
    const bool bf16_head = (ws_size >= need_bytes);

    gather_rows<<<M, 256, 0, stream>>>(tokens, emb, x);

    for (int l = 0; l < LL; l++) {
        const float* wq = Wq + (size_t)l * DD * DD;
        const float* wk = Wk + (size_t)l * DD * DD;
        const float* wv = Wv + (size_t)l * DD * DD;
        const float* wb = Wb + (size_t)l * DD;
        const float* wo = Wo + (size_t)l * DD * DD;
        const float* rw = rms_w + (size_t)l * DD;

        dim3 g64(DD / 64, M / 64);
        sgemm<64, 64, 16, 4, 4><<<g64, 256, 0, stream>>>(x, wq, qb, M, DD, DD);
        silu_l2norm_kernel<<<M, 256, 0, stream>>>(qb);
        sgemm<64, 64, 16, 4, 4><<<g64, 256, 0, stream>>>(x, wk, kb, M, DD, DD);
        silu_l2norm_kernel<<<M, 256, 0, stream>>>(kb);
        sgemm<64, 64, 16, 4, 4><<<g64, 256, 0, stream>>>(x, wv, vb, M, DD, DD);
        silu_kernel<<<(M * DD + 255) / 256, 256, 0, stream>>>(vb, M * DD);
        beta_kernel<<<M, 256, 0, stream>>>(x, wb, betab);

        delta_scan_kernel<<<BB * (DD / 4), 256, 0, stream>>>(qb, kb, vb, betab, ob);

        rmsnorm_kernel<<<M, 256, 0, stream>>>(ob, rw);
        sgemm<64, 64, 16, 4, 4><<<g64, 256, 0, stream>>>(ob, wo, x, M, DD, DD);
    }

    layernorm_kernel<<<M, 256, 0, stream>>>(x, ln_g, ln_b, xn);

    if (bf16_head) {
        f32_to_bf16_vec<<<(M * DD / 4 + 255) / 256, 256, 0, stream>>>(xn, xnb, M * DD / 4);
        transpose_f32_bf16<<<dim3(VV / 32, DD / 32), 256, 0, stream>>>(head_w, hwb, DD, VV);
        gemm_bf16_tn<<<dim3(VV / 128, M / 128), 256, 0, stream>>>(xnb, hwb, out, M, VV, DD);
    } else {
        dim3 ghead(VV / 128, M / 128);
        sgemm<128, 128, 8, 8, 8><<<ghead, 256, 0, stream>>>(xn, head_w, out, M, VV, DD);
    }
}

// Round 3
// 3250.598 us; speedup vs baseline: 1.1998x; 1.1998x over previous
//
#include <hip/hip_runtime.h>
#include <hip/hip_bf16.h>

// ---------------------------------------------------------------------------
// DeltaNet forward. B=2, S=1024, D=1024, L=2, V=32000.
// R1: head GEMM -> bf16 MFMA (verified, absmax unchanged).
// R2: LDS-staged scan FAILED (1195->1377us): per-step vmcnt(0)+barrier lockstep
//     exposed cache latency; b128 conflicts only dropped 3x.
// R3: scan -> one wave per (batch,column), ZERO inter-wave communication:
//     state in registers (Sl[16]/lane), k/q read as coalesced float4 from
//     global (L1/L2-resident stream), register double-buffer w/ unroll-2,
//     no LDS, no barriers. Compiler places vmcnt at first-use -> natural
//     software pipeline. Layer GEMMs stay fp32 this round.
// ---------------------------------------------------------------------------

#define DD 1024
#define BB 2
#define SS 1024
#define LL 2
#define VV 32000

typedef __attribute__((ext_vector_type(8))) short bf16x8;
typedef __attribute__((ext_vector_type(4))) float f32x4;

__device__ __forceinline__ float sigmoidf_(float x) { return 1.0f / (1.0f + expf(-x)); }

// round-to-nearest-even f32 -> bf16
__device__ __forceinline__ unsigned short f2bf(float f) {
    unsigned int u = __float_as_uint(f);
    u += 0x7fffu + ((u >> 16) & 1u);
    return (unsigned short)(u >> 16);
}

// ---------------- embedding gather ----------------
__global__ __launch_bounds__(256) void gather_rows(const int* __restrict__ tokens,
                                                   const float* __restrict__ emb,
                                                   float* __restrict__ x) {
    int row = blockIdx.x;
    int tok = tokens[row];
    const float4* src = (const float4*)(emb + (size_t)tok * DD);
    float4* dst = (float4*)(x + (size_t)row * DD);
    for (int i = threadIdx.x; i < DD / 4; i += 256) dst[i] = src[i];
}

// ---------------- generic tiled SGEMM (fp32, layer GEMMs) ----------------
template <int BM, int BN, int BK, int TM, int TN>
__global__ __launch_bounds__(256) void sgemm(const float* __restrict__ A,
                                             const float* __restrict__ B,
                                             float* __restrict__ C,
                                             int M, int N, int K) {
    constexpr int THREADS = (BM / TM) * (BN / TN);
    static_assert(THREADS == 256, "block must be 256");
    __shared__ float As[BK][BM + 4];
    __shared__ float Bs[BK][BN + 4];

    const int tid = threadIdx.x;
    const int tx = tid % (BN / TN);
    const int ty = tid / (BN / TN);
    const int row0 = blockIdx.y * BM;
    const int col0 = blockIdx.x * BN;

    float acc[TM][TN] = {};

    for (int k0 = 0; k0 < K; k0 += BK) {
        constexpr int A4 = BM * BK / 4;
        #pragma unroll
        for (int i = tid; i < A4; i += THREADS) {
            int r = i / (BK / 4);
            int q = i % (BK / 4);
            float4 f = *(const float4*)&A[(size_t)(row0 + r) * K + k0 + q * 4];
            As[q * 4 + 0][r] = f.x;
            As[q * 4 + 1][r] = f.y;
            As[q * 4 + 2][r] = f.z;
            As[q * 4 + 3][r] = f.w;
        }
        constexpr int B4 = BK * BN / 4;
        #pragma unroll
        for (int i = tid; i < B4; i += THREADS) {
            int r = i / (BN / 4);
            int q = i % (BN / 4);
            float4 f = *(const float4*)&B[(size_t)(k0 + r) * N + col0 + q * 4];
            *(float4*)&Bs[r][q * 4] = f;
        }
        __syncthreads();

        #pragma unroll
        for (int kr = 0; kr < BK; kr++) {
            float a[TM], b[TN];
            #pragma unroll
            for (int i = 0; i < TM; i += 4)
                *(float4*)&a[i] = *(const float4*)&As[kr][ty * TM + i];
            #pragma unroll
            for (int j = 0; j < TN; j += 4)
                *(float4*)&b[j] = *(const float4*)&Bs[kr][tx * TN + j];
            #pragma unroll
            for (int i = 0; i < TM; i++)
                #pragma unroll
                for (int j = 0; j < TN; j++)
                    acc[i][j] += a[i] * b[j];
        }
        __syncthreads();
    }

    #pragma unroll
    for (int i = 0; i < TM; i++)
        #pragma unroll
        for (int j = 0; j < TN; j += 4) {
            float4 f = {acc[i][j], acc[i][j + 1], acc[i][j + 2], acc[i][j + 3]};
            *(float4*)&C[(size_t)(row0 + ty * TM + i) * N + col0 + tx * TN + j] = f;
        }
}

// ---------------- bf16 MFMA GEMM (head) ----------------
__global__ __launch_bounds__(256) void gemm_bf16_tn(const unsigned short* __restrict__ A,
                                                    const unsigned short* __restrict__ Bt,
                                                    float* __restrict__ C,
                                                    int M, int N, int K) {
    __shared__ __align__(16) unsigned short As[128 * 32];
    __shared__ __align__(16) unsigned short Bs[128 * 32];

    const int tid = threadIdx.x;
    const int wave = tid >> 6;
    const int lane = tid & 63;
    const int row0 = blockIdx.y * 128;
    const int col0 = blockIdx.x * 128;
    const int wm = wave >> 1;
    const int wn = wave & 1;
    const int g = lane >> 4;
    const int fr = lane & 15;

    const int lr = lane >> 2;
    const int lk = (lane & 3) * 8;

    f32x4 acc[4][4] = {};

    for (int k0 = 0; k0 < K; k0 += 32) {
        __syncthreads();
        #pragma unroll
        for (int i = 0; i < 2; i++) {
            const int iss = wave * 2 + i;
            const unsigned short* ga = A + (size_t)(row0 + iss * 16 + lr) * K + k0 + lk;
            __builtin_amdgcn_global_load_lds(
                (const __attribute__((address_space(1))) void*)ga,
                (__attribute__((address_space(3))) void*)(As + iss * 512), 16, 0, 0);
            const unsigned short* gb = Bt + (size_t)(col0 + iss * 16 + lr) * K + k0 + lk;
            __builtin_amdgcn_global_load_lds(
                (const __attribute__((address_space(1))) void*)gb,
                (__attribute__((address_space(3))) void*)(Bs + iss * 512), 16, 0, 0);
        }
        __syncthreads();

        bf16x8 a[4], b[4];
        #pragma unroll
        for (int i = 0; i < 4; i++)
            a[i] = *(const bf16x8*)&As[(wm * 64 + i * 16 + fr) * 32 + g * 8];
        #pragma unroll
        for (int j = 0; j < 4; j++)
            b[j] = *(const bf16x8*)&Bs[(wn * 64 + j * 16 + fr) * 32 + g * 8];
        #pragma unroll
        for (int i = 0; i < 4; i++)
            #pragma unroll
            for (int j = 0; j < 4; j++)
                acc[i][j] = __builtin_amdgcn_mfma_f32_16x16x32_bf16(a[i], b[j], acc[i][j], 0, 0, 0);
    }

    #pragma unroll
    for (int i = 0; i < 4; i++) {
        const int rbase = row0 + wm * 64 + i * 16 + g * 4;
        #pragma unroll
        for (int j = 0; j < 4; j++) {
            const int c = col0 + wn * 64 + j * 16 + fr;
            #pragma unroll
            for (int ii = 0; ii < 4; ii++)
                C[(size_t)(rbase + ii) * N + c] = acc[i][j][ii];
        }
    }
}

// ---------------- f32 -> bf16 converters ----------------
__global__ __launch_bounds__(256) void f32_to_bf16_vec(const float* __restrict__ in,
                                                       unsigned short* __restrict__ out,
                                                       int n4) {
    int i = blockIdx.x * 256 + threadIdx.x;
    if (i < n4) {
        float4 f = ((const float4*)in)[i];
        ushort4 u = {f2bf(f.x), f2bf(f.y), f2bf(f.z), f2bf(f.w)};
        ((ushort4*)out)[i] = u;
    }
}

__global__ __launch_bounds__(256) void transpose_f32_bf16(const float* __restrict__ in,
                                                          unsigned short* __restrict__ out,
                                                          int K, int N) {
    __shared__ float tile[32][33];
    const int nb = blockIdx.x;
    const int kb = blockIdx.y;
    const int tx = threadIdx.x & 31;
    const int ty = threadIdx.x >> 5;
    #pragma unroll
    for (int i = 0; i < 32; i += 8)
        tile[ty + i][tx] = in[(size_t)(kb * 32 + ty + i) * N + nb * 32 + tx];
    __syncthreads();
    #pragma unroll
    for (int i = 0; i < 32; i += 8)
        out[(size_t)(nb * 32 + ty + i) * K + kb * 32 + tx] = f2bf(tile[tx][ty + i]);
}

// ---------------- activations ----------------
__global__ __launch_bounds__(256) void silu_l2norm_kernel(float* __restrict__ buf) {
    __shared__ float tmp[4];
    size_t base = (size_t)blockIdx.x * DD;
    float vals[4];
    float ss = 0.0f;
    #pragma unroll
    for (int i = 0; i < 4; i++) {
        float xv = buf[base + threadIdx.x + i * 256];
        float s = xv * sigmoidf_(xv);
        vals[i] = s;
        ss += s * s;
    }
    #pragma unroll
    for (int off = 32; off; off >>= 1) ss += __shfl_xor(ss, off);
    if ((threadIdx.x & 63) == 0) tmp[threadIdx.x >> 6] = ss;
    __syncthreads();
    ss = tmp[0] + tmp[1] + tmp[2] + tmp[3];
    float sc = rsqrtf(ss + 1e-6f);
    #pragma unroll
    for (int i = 0; i < 4; i++) buf[base + threadIdx.x + i * 256] = vals[i] * sc;
}

__global__ __launch_bounds__(256) void silu_kernel(float* __restrict__ buf, int n) {
    int i = blockIdx.x * 256 + threadIdx.x;
    if (i < n) {
        float xv = buf[i];
        buf[i] = xv * sigmoidf_(xv);
    }
}

__global__ __launch_bounds__(256) void beta_kernel(const float* __restrict__ x,
                                                   const float* __restrict__ wb,
                                                   float* __restrict__ beta) {
    __shared__ float tmp[4];
    size_t base = (size_t)blockIdx.x * DD;
    float s = 0.0f;
    #pragma unroll
    for (int i = 0; i < 4; i++) {
        int idx = threadIdx.x + i * 256;
        s += x[base + idx] * wb[idx];
    }
    #pragma unroll
    for (int off = 32; off; off >>= 1) s += __shfl_xor(s, off);
    if ((threadIdx.x & 63) == 0) tmp[threadIdx.x >> 6] = s;
    __syncthreads();
    if (threadIdx.x == 0) beta[blockIdx.x] = sigmoidf_(tmp[0] + tmp[1] + tmp[2] + tmp[3]);
}

__global__ __launch_bounds__(256) void rmsnorm_kernel(float* __restrict__ buf,
                                                      const float* __restrict__ w) {
    __shared__ float tmp[4];
    size_t base = (size_t)blockIdx.x * DD;
    float vals[4];
    float ss = 0.0f;
    #pragma unroll
    for (int i = 0; i < 4; i++) {
        float xv = buf[base + threadIdx.x + i * 256];
        vals[i] = xv;
        ss += xv * xv;
    }
    #pragma unroll
    for (int off = 32; off; off >>= 1) ss += __shfl_xor(ss, off);
    if ((threadIdx.x & 63) == 0) tmp[threadIdx.x >> 6] = ss;
    __syncthreads();
    ss = tmp[0] + tmp[1] + tmp[2] + tmp[3];
    float sc = rsqrtf(ss * (1.0f / DD) + 1e-5f);
    #pragma unroll
    for (int i = 0; i < 4; i++) {
        int idx = threadIdx.x + i * 256;
        buf[base + idx] = vals[i] * sc * w[idx];
    }
}

__global__ __launch_bounds__(256) void layernorm_kernel(const float* __restrict__ in,
                                                        const float* __restrict__ g,
                                                        const float* __restrict__ b,
                                                        float* __restrict__ out) {
    __shared__ float tmp[4];
    size_t base = (size_t)blockIdx.x * DD;
    float vals[4];
    float s = 0.0f;
    #pragma unroll
    for (int i = 0; i < 4; i++) {
        float xv = in[base + threadIdx.x + i * 256];
        vals[i] = xv;
        s += xv;
    }
    #pragma unroll
    for (int off = 32; off; off >>= 1) s += __shfl_xor(s, off);
    if ((threadIdx.x & 63) == 0) tmp[threadIdx.x >> 6] = s;
    __syncthreads();
    float mu = (tmp[0] + tmp[1] + tmp[2] + tmp[3]) * (1.0f / DD);
    float vs = 0.0f;
    #pragma unroll
    for (int i = 0; i < 4; i++) {
        float c = vals[i] - mu;
        vals[i] = c;
        vs += c * c;
    }
    #pragma unroll
    for (int off = 32; off; off >>= 1) vs += __shfl_xor(vs, off);
    __syncthreads();
    if ((threadIdx.x & 63) == 0) tmp[threadIdx.x >> 6] = vs;
    __syncthreads();
    float var = (tmp[0] + tmp[1] + tmp[2] + tmp[3]) * (1.0f / DD);
    float sc = rsqrtf(var + 1e-5f);
    #pragma unroll
    for (int i = 0; i < 4; i++) {
        int idx = threadIdx.x + i * 256;
        out[base + idx] = vals[i] * sc * g[idx] + b[idx];
    }
}

// ---------------- delta-rule scan (R3) ----------------
// One wave per (batch, value-column). Lane owns d = r4*256 + lane*4 + j
// (r4,j in 0..3): 16 state rows Sl[16] in registers. Per step: 8 coalesced
// float4 global loads (k,q row, L1/L2-resident), 3 merged dots, one 6-level
// butterfly (3 interleaved chains), rank-1 update. Register double-buffer
// via unroll-2; NO LDS, NO barriers, NO explicit waitcnt.
#define DS_STEP(KK, QQ, BT, VT, ROWOFF)                                      \
  {                                                                          \
    float pk4[4], pq4[4], pqk4[4];                                           \
    _Pragma("unroll") for (int r4 = 0; r4 < 4; r4++) {                       \
      pk4[r4] = KK[r4 * 4] * Sl[r4 * 4];                                     \
      pq4[r4] = QQ[r4 * 4] * Sl[r4 * 4];                                     \
      pqk4[r4] = QQ[r4 * 4] * KK[r4 * 4];                                    \
      _Pragma("unroll") for (int j = 1; j < 4; j++) {                        \
        pk4[r4] += KK[r4 * 4 + j] * Sl[r4 * 4 + j];                          \
        pq4[r4] += QQ[r4 * 4 + j] * Sl[r4 * 4 + j];                          \
        pqk4[r4] += QQ[r4 * 4 + j] * KK[r4 * 4 + j];                         \
      }                                                                      \
    }                                                                        \
    float pk = (pk4[0] + pk4[1]) + (pk4[2] + pk4[3]);                        \
    float pq = (pq4[0] + pq4[1]) + (pq4[2] + pq4[3]);                        \
    float pqk = (pqk4[0] + pqk4[1]) + (pqk4[2] + pqk4[3]);                   \
    _Pragma("unroll") for (int off = 32; off; off >>= 1) {                   \
      pk += __shfl_xor(pk, off);                                             \
      pq += __shfl_xor(pq, off);                                             \
      pqk += __shfl_xor(pqk, off);                                           \
    }                                                                        \
    float u = (BT) * ((VT)-pk);                                              \
    float op = pq + pqk * u; /* == q . (S_old + k u) */                      \
    _Pragma("unroll") for (int r = 0; r < 16; r++) Sl[r] += KK[r] * u;       \
    if (lane == 0) o[(ROWOFF) + col] = op;                                   \
  }

__global__ __launch_bounds__(64) void delta_scan_kernel(const float* __restrict__ q,
                                                        const float* __restrict__ k,
                                                        const float* __restrict__ v,
                                                        const float* __restrict__ beta,
                                                        float* __restrict__ o) {
    const int gid = blockIdx.x;          // 0 .. BB*DD-1
    const int batch = gid >> 10;         // gid / DD
    const int col = gid & (DD - 1);
    const int lane = threadIdx.x;        // 0..63
    const size_t base = (size_t)batch * SS * DD;
    const int doff = lane * 4;

    float Sl[16];
    #pragma unroll
    for (int r = 0; r < 16; r++) Sl[r] = 0.0f;

    float kA[16], qA[16], kB[16], qB[16];
    float btA, vtA, btB, vtB;

    // prefetch t=0 into A
    #pragma unroll
    for (int r4 = 0; r4 < 4; r4++) {
        *(float4*)&kA[r4 * 4] = *(const float4*)&k[base + r4 * 256 + doff];
        *(float4*)&qA[r4 * 4] = *(const float4*)&q[base + r4 * 256 + doff];
    }
    btA = beta[batch * SS];
    vtA = v[base + col];

    for (int t = 0; t < SS; t += 2) {
        const size_t row0 = base + (size_t)t * DD;

        // prefetch t+1 into B (SS even -> always in range)
        #pragma unroll
        for (int r4 = 0; r4 < 4; r4++) {
            *(float4*)&kB[r4 * 4] = *(const float4*)&k[row0 + DD + r4 * 256 + doff];
            *(float4*)&qB[r4 * 4] = *(const float4*)&q[row0 + DD + r4 * 256 + doff];
        }
        btB = beta[batch * SS + t + 1];
        vtB = v[row0 + DD + col];

        // step t (A)
        DS_STEP(kA, qA, btA, vtA, row0)

        // prefetch t+2 into A
        if (t + 2 < SS) {
            #pragma unroll
            for (int r4 = 0; r4 < 4; r4++) {
                *(float4*)&kA[r4 * 4] = *(const float4*)&k[row0 + 2 * DD + r4 * 256 + doff];
                *(float4*)&qA[r4 * 4] = *(const float4*)&q[row0 + 2 * DD + r4 * 256 + doff];
            }
            btA = beta[batch * SS + t + 2];
            vtA = v[row0 + 2 * DD + col];
        }

        // step t+1 (B)
        DS_STEP(kB, qB, btB, vtB, row0 + DD)
    }
}

// ---------------------------------------------------------------------------
extern "C" void kernel_launch(void* const* d_in, const int* in_sizes, int n_in,
                              void* d_out, int out_size, void* d_ws, size_t ws_size,
                              hipStream_t stream) {
    const int* tokens   = (const int*)d_in[0];
    const float* emb    = (const float*)d_in[1];
    const float* Wq     = (const float*)d_in[2];
    const float* Wk     = (const float*)d_in[3];
    const float* Wv     = (const float*)d_in[4];
    const float* Wb     = (const float*)d_in[5];
    const float* Wo     = (const float*)d_in[6];
    const float* rms_w  = (const float*)d_in[7];
    const float* ln_g   = (const float*)d_in[8];
    const float* ln_b   = (const float*)d_in[9];
    const float* head_w = (const float*)d_in[10];
    float* out = (float*)d_out;

    const int M = BB * SS;  // 2048
    const size_t ND = (size_t)M * DD;

    float* ws    = (float*)d_ws;
    float* x     = ws;
    float* qb    = ws + ND;
    float* kb    = ws + 2 * ND;
    float* vb    = ws + 3 * ND;
    float* ob    = ws + 4 * ND;
    float* xn    = ws + 5 * ND;
    float* betab = ws + 6 * ND;  // M floats

    unsigned short* xnb = (unsigned short*)(ws + 6 * ND + M);
    unsigned short* hwb = xnb + (size_t)M * DD;
    const size_t need_bytes = (6 * ND + M) * sizeof(float) +
                              ((size_t)M * DD + (size_t)VV * DD) * sizeof(unsigned short);
    const bool bf16_head = (ws_size >= need_bytes);

    gather_rows<<<M, 256, 0, stream>>>(tokens, emb, x);

    for (int l = 0; l < LL; l++) {
        const float* wq = Wq + (size_t)l * DD * DD;
        const float* wk = Wk + (size_t)l * DD * DD;
        const float* wv = Wv + (size_t)l * DD * DD;
        const float* wb = Wb + (size_t)l * DD;
        const float* wo = Wo + (size_t)l * DD * DD;
        const float* rw = rms_w + (size_t)l * DD;

        dim3 g64(DD / 64, M / 64);
        sgemm<64, 64, 16, 4, 4><<<g64, 256, 0, stream>>>(x, wq, qb, M, DD, DD);
        silu_l2norm_kernel<<<M, 256, 0, stream>>>(qb);
        sgemm<64, 64, 16, 4, 4><<<g64, 256, 0, stream>>>(x, wk, kb, M, DD, DD);
        silu_l2norm_kernel<<<M, 256, 0, stream>>>(kb);
        sgemm<64, 64, 16, 4, 4><<<g64, 256, 0, stream>>>(x, wv, vb, M, DD, DD);
        silu_kernel<<<(M * DD + 255) / 256, 256, 0, stream>>>(vb, M * DD);
        beta_kernel<<<M, 256, 0, stream>>>(x, wb, betab);

        delta_scan_kernel<<<BB * DD, 64, 0, stream>>>(qb, kb, vb, betab, ob);

        rmsnorm_kernel<<<M, 256, 0, stream>>>(ob, rw);
        sgemm<64, 64, 16, 4, 4><<<g64, 256, 0, stream>>>(ob, wo, x, M, DD, DD);
    }

    layernorm_kernel<<<M, 256, 0, stream>>>(x, ln_g, ln_b, xn);

    if (bf16_head) {
        f32_to_bf16_vec<<<(M * DD / 4 + 255) / 256, 256, 0, stream>>>(xn, xnb, M * DD / 4);
        transpose_f32_bf16<<<dim3(VV / 32, DD / 32), 256, 0, stream>>>(head_w, hwb, DD, VV);
        gemm_bf16_tn<<<dim3(VV / 128, M / 128), 256, 0, stream>>>(xnb, hwb, out, M, VV, DD);
    } else {
        dim3 ghead(VV / 128, M / 128);
        sgemm<128, 128, 8, 8, 8><<<ghead, 256, 0, stream>>>(xn, head_w, out, M, VV, DD);
    }
}